// Round 9
// baseline (16302.094 us; speedup 1.0000x reference)
//
#include <hip/hip_runtime.h>
#include <cmath>

#define SEQ  256
#define BATCH 128
#define FEAT 512
#define HID  1024
#define G4   4096
#define BH (BATCH*HID)

typedef __attribute__((ext_vector_type(8))) _Float16 f16x8;
typedef __attribute__((ext_vector_type(4))) float f32x4;

__device__ __forceinline__ unsigned short f16_rne(float f) {
  _Float16 h = (_Float16)f;
  return __builtin_bit_cast(unsigned short, h);
}
__device__ __forceinline__ float f16_tof(unsigned short s) {
  return (float)__builtin_bit_cast(_Float16, s);
}
__device__ __forceinline__ void gload16(const unsigned short* g, unsigned short* l) {
  __builtin_amdgcn_global_load_lds(
      (const __attribute__((address_space(1))) unsigned int*)g,
      (__attribute__((address_space(3))) unsigned int*)l, 16, 0, 0);
}
__device__ __forceinline__ float sigf(float x) { return 1.f/(1.f+expf(-x)); }

// ---------------- setup kernels (once per call) ----------------

__global__ __launch_bounds__(256)
void conv16(const float* __restrict__ src, unsigned short* __restrict__ dst, int n4) {
  for (int i = blockIdx.x*256 + threadIdx.x; i < n4; i += gridDim.x*256) {
    const float4 v = ((const float4*)src)[i];
    ushort4 h;
    h.x = f16_rne(v.x); h.y = f16_rne(v.y); h.z = f16_rne(v.z); h.w = f16_rne(v.w);
    ((ushort4*)dst)[i] = h;
  }
}

__global__ __launch_bounds__(256)
void conv16_hilo(const float* __restrict__ src, unsigned short* __restrict__ hi,
                 unsigned short* __restrict__ lo, int n4) {
  for (int i = blockIdx.x*256 + threadIdx.x; i < n4; i += gridDim.x*256) {
    const float4 v = ((const float4*)src)[i];
    ushort4 h, l;
    h.x = f16_rne(v.x); l.x = f16_rne(v.x - f16_tof(h.x));
    h.y = f16_rne(v.y); l.y = f16_rne(v.y - f16_tof(h.y));
    h.z = f16_rne(v.z); l.z = f16_rne(v.z - f16_tof(h.z));
    h.w = f16_rne(v.w); l.w = f16_rne(v.w - f16_tof(h.w));
    ((ushort4*)hi)[i] = h; ((ushort4*)lo)[i] = l;
  }
}

// WoutT[c][k] = f16(Wout[k][c])
__global__ __launch_bounds__(256)
void transp16(const float* __restrict__ src, unsigned short* __restrict__ dst) {
  const int i = blockIdx.x*256 + threadIdx.x;   // 1M
  const int k = i >> 10, c = i & 1023;
  dst[(c << 10) + k] = f16_rne(src[i]);
}

// f32 -> f16 with gate-row permutation: r = g*1024+n -> prow = n*4+g
__global__ __launch_bounds__(256)
void conv_perm16(const float* __restrict__ src, unsigned short* __restrict__ dst,
                 int n4, int ksh) {
  for (int i = blockIdx.x*256 + threadIdx.x; i < n4; i += gridDim.x*256) {
    const float4 v = ((const float4*)src)[i];
    const int row = i >> ksh, cq = i & ((1 << ksh) - 1);
    const int prow = ((row & 1023) << 2) | (row >> 10);
    ushort4 h;
    h.x = f16_rne(v.x); h.y = f16_rne(v.y); h.z = f16_rne(v.z); h.w = f16_rne(v.w);
    ((ushort4*)dst)[(prow << ksh) + cq] = h;
  }
}

// bperm[l][prow] = bih + bhh (gate-permuted, f32)
__global__ __launch_bounds__(256)
void bias_perm(const float* __restrict__ bih, const float* __restrict__ bhh,
               float* __restrict__ bperm) {
  const int i = blockIdx.x*256 + threadIdx.x;
  if (i >= 3*G4) return;
  const int l = i >> 12, r = i & 4095;
  const int prow = ((r & 1023) << 2) | (r >> 10);
  bperm[(l << 12) + prow] = bih[i] + bhh[i];
}

__global__ __launch_bounds__(256)
void bcopy(const float* __restrict__ b, float* __restrict__ dst) {
  const int i = blockIdx.x*256 + threadIdx.x;
  if (i < HID) dst[i] = b[i];
}

// dst[perm?prow(r):r] += W[r,:] . b   (f32 weights)
__global__ __launch_bounds__(256)
void gemvf(const float* __restrict__ W, const float* __restrict__ b,
           float* __restrict__ dst, int nrows, int perm) {
  const int r = blockIdx.x*256 + threadIdx.x;
  if (r >= nrows) return;
  const float4* wr = (const float4*)(W + (size_t)r*HID);
  float acc = 0.f;
  for (int k = 0; k < 256; ++k) {
    const float4 w = wr[k]; const float4 bb = ((const float4*)b)[k];
    acc += w.x*bb.x + w.y*bb.y + w.z*bb.z + w.w*bb.w;
  }
  const int o = perm ? (((r & 1023) << 2) | (r >> 10)) : r;
  dst[o] += acc;
}

// dst[perm?prow(r):r] += W16[r,:] . b   (f16 weights)
__global__ __launch_bounds__(256)
void gemvh(const unsigned short* __restrict__ W, const float* __restrict__ b,
           float* __restrict__ dst, int nrows, int perm) {
  const int r = blockIdx.x*256 + threadIdx.x;
  if (r >= nrows) return;
  const ushort4* wr = (const ushort4*)(W + (size_t)r*HID);
  float acc = 0.f;
  for (int k = 0; k < 256; ++k) {
    const ushort4 w = wr[k]; const float4 bb = ((const float4*)b)[k];
    acc += f16_tof(w.x)*bb.x + f16_tof(w.y)*bb.y + f16_tof(w.z)*bb.z + f16_tof(w.w)*bb.w;
  }
  const int o = perm ? (((r & 1023) << 2) | (r >> 10)) : r;
  dst[o] += acc;
}

// ---------------- 3-segment split-precision f16 MFMA GEMM core ----------------
// Fixed geometry: BM=128, BN=256, BK=64; 8 waves (2x4), wave tile 64x64
// (MI=4, NI=4 frags of 16x16x32). P2: Ah*W + Al*W; !P2: Ah*W.
// Segments: kg<K1 -> (A0,W0,stride K1); <K1+1024 -> (A1,W1,1024); else (A2,W2,1024).
// Double-buffered LDS (128 KB) + global_load_lds(16B) + XOR-(row&7) swizzle.
template<bool P2>
__device__ __forceinline__ void mm_core3(
    unsigned short* lds, int n0, int kstart, int nch, int K1,
    const unsigned short* A0h, const unsigned short* A0l,
    const unsigned short* A1h, const unsigned short* A1l,
    const unsigned short* A2h, const unsigned short* A2l,
    const unsigned short* W0, const unsigned short* W1, const unsigned short* W2,
    f32x4 acc[4][4])
{
  constexpr int OAl = 8192, OW = 16384, STRIDE = 32768;   // ushorts
  const int tid = threadIdx.x;
  const int lane = tid & 63, wave = tid >> 6;
  const int wr = wave >> 2, wc = wave & 3;
  const int rl = lane >> 3, cc = lane & 7;
  const int gcol = (cc ^ rl) << 3;

  auto stage = [&](int ch) {
    const int kg = kstart + (ch << 6);
    const unsigned short *pAh, *pAl, *pW; int sA;
    if (kg < K1)           { pAh=A0h+kg; pAl=A0l+kg; pW=W0+kg; sA=K1; }
    else if (kg < K1+1024) { const int o=kg-K1;      pAh=A1h+o; pAl=A1l+o; pW=W1+o; sA=1024; }
    else                   { const int o=kg-K1-1024; pAh=A2h+o; pAl=A2l+o; pW=W2+o; sA=1024; }
    unsigned short* const db = lds + (ch & 1)*STRIDE;
    #pragma unroll
    for (int q = 0; q < 8; ++q) {
      const int g = wave*8 + q;     // 64 groups of 8 rows: [0,16) Ah, [16,32) Al, [32,64) W
      if (g < 16)      gload16(pAh + (size_t)(g*8 + rl)*sA + gcol,            db + g*512);
      else if (g < 32) gload16(pAl + (size_t)((g-16)*8 + rl)*sA + gcol,       db + g*512);
      else             gload16(pW  + (size_t)(n0 + (g-32)*8 + rl)*sA + gcol,  db + g*512);
    }
  };

  stage(0);
  for (int ch = 0; ch < nch; ++ch) {
    if (ch + 1 < nch) {
      stage(ch + 1);
      asm volatile("s_waitcnt vmcnt(8)" ::: "memory");
    } else {
      asm volatile("s_waitcnt vmcnt(0)" ::: "memory");
    }
    __builtin_amdgcn_sched_barrier(0);
    __builtin_amdgcn_s_barrier();
    const unsigned short* const cb = lds + (ch & 1)*STRIDE;
    #pragma unroll
    for (int kh = 0; kh < 2; ++kh) {
      const int j0 = (kh << 2) + (lane >> 4);
      f16x8 ah[4], al[4], bh[4];
      #pragma unroll
      for (int mi = 0; mi < 4; ++mi) {
        const int row = (wr << 6) + (mi << 4) + (lane & 15);
        const int off = row*64 + ((j0 ^ (row & 7)) << 3);
        ah[mi] = *(const f16x8*)(cb + off);
        if constexpr (P2) al[mi] = *(const f16x8*)(cb + OAl + off);
      }
      #pragma unroll
      for (int ni = 0; ni < 4; ++ni) {
        const int wrow = (wc << 6) + (ni << 4) + (lane & 15);
        const int off = wrow*64 + ((j0 ^ (wrow & 7)) << 3);
        bh[ni] = *(const f16x8*)(cb + OW + off);
      }
      #pragma unroll
      for (int mi = 0; mi < 4; ++mi)
        #pragma unroll
        for (int ni = 0; ni < 4; ++ni) {
          acc[mi][ni] = __builtin_amdgcn_mfma_f32_16x16x32_f16(ah[mi], bh[ni], acc[mi][ni], 0,0,0);
          if constexpr (P2)
            acc[mi][ni] = __builtin_amdgcn_mfma_f32_16x16x32_f16(al[mi], bh[ni], acc[mi][ni], 0,0,0);
        }
    }
    __builtin_amdgcn_s_barrier();
  }
}

// ---------------- weight-fold GEMM: dst = A(f16) @ WoutT, optional perm ----------------
__global__ __launch_bounds__(512, 2)
void wfuse_kernel(const unsigned short* __restrict__ A,
                  const unsigned short* __restrict__ WT,
                  unsigned short* __restrict__ dstU,   // nullable
                  unsigned short* __restrict__ dstP)   // nullable (gate-perm rows)
{
  __shared__ unsigned short smem[2*32768];
  const int mb = blockIdx.x, jy = blockIdx.y;
  const unsigned short* Ar = A + (size_t)(mb*128)*HID;
  f32x4 z4 = {0.f,0.f,0.f,0.f};
  f32x4 acc[4][4];
  #pragma unroll
  for (int a = 0; a < 4; ++a) { acc[a][0]=z4; acc[a][1]=z4; acc[a][2]=z4; acc[a][3]=z4; }
  mm_core3<false>(smem, jy << 8, 0, 16, 1024,
                  Ar, Ar, Ar, Ar, Ar, Ar, WT, WT, WT, acc);

  const int lane = threadIdx.x & 63, wave = threadIdx.x >> 6;
  const int wr = wave >> 2, wc = wave & 3;
  const int rb = (lane >> 4) << 2, cbl = lane & 15;
  #pragma unroll
  for (int mi = 0; mi < 4; ++mi)
    #pragma unroll
    for (int ni = 0; ni < 4; ++ni)
      #pragma unroll
      for (int r = 0; r < 4; ++r) {
        const int row = mb*128 + (wr << 6) + (mi << 4) + rb + r;
        const int col = (jy << 8) + (wc << 6) + (ni << 4) + cbl;
        const unsigned short v = f16_rne(acc[mi][ni][r]);
        if (dstU) dstU[((size_t)row << 10) + col] = v;
        if (dstP) dstP[((size_t)(((row & 1023) << 2) | (row >> 10)) << 10) + col] = v;
      }
}

// ---------------- the per-diagonal kernel (single launch per diag) ----------------
// 232 blocks: [0,48)   l=0 gates: jt=bid/3,  kz=bid%3 (KZ=3), K=1536 = x|h0
//             [48,112) l=1 gates: jt,kz of 4 (KZ=4),          K=2048 = h0|h1
//             [112,208) l=2 gates: jt,kz of 6 (KZ=6),         K=3072 = h1|h0(d-2)|h2
//             [208,232) out:      jt(0..3),kz of 6 (KZ=6),    K=3072 = h2|h1(d-2)|h0(d-3)
// Gate weights are gate-row-permuted (col = n*4+g) so each 256-wide tile owns
// all 4 gates of 64 n-values -> cell runs in the reducing block's epilogue.
__global__ __launch_bounds__(512, 2)
void diag_kernel(int d,
    const unsigned short* __restrict__ xh, const unsigned short* __restrict__ xl,
    const unsigned short* __restrict__ hH, const unsigned short* __restrict__ hL, // ring [4][3][BH]
    unsigned short* __restrict__ hHw, unsigned short* __restrict__ hLw,
    const unsigned short* __restrict__ Wih0p, const unsigned short* __restrict__ Whhp,
    const unsigned short* __restrict__ Wf1p,  const unsigned short* __restrict__ Wf2p,
    const unsigned short* __restrict__ Wff2p,
    const unsigned short* __restrict__ WoutC, const unsigned short* __restrict__ Wo2u,
    const unsigned short* __restrict__ Wo3u,
    const float* __restrict__ bperm, const float* __restrict__ bconst,
    float* __restrict__ cst, float* __restrict__ gpart,
    unsigned* __restrict__ tk, float* __restrict__ out)
{
  __shared__ unsigned short smem[2*32768];
  __shared__ unsigned lastf;
  const int bid = blockIdx.x, tid = threadIdx.x;

  int l, jt, kz, KZ, gid;
  if (bid < 48)       { l=0; jt=bid/3;              kz=bid%3;        KZ=3; gid=jt; }
  else if (bid < 112) { l=1; int u=bid-48;  jt=u>>2; kz=u&3;         KZ=4; gid=16+jt; }
  else if (bid < 208) { l=2; int u=bid-112; jt=u/6; kz=u%6;          KZ=6; gid=32+jt; }
  else                { l=3; int u=bid-208; jt=u/6; kz=u%6;          KZ=6; gid=48+jt; }
  const bool isout = (l == 3);
  const int t = d - (isout ? 3 : l);
  if (t < 0 || t >= SEQ) return;

  const int s1 = (d-1)&3, s2 = (d-2)&3, s3 = (d-3)&3;
  auto hp = [&](const unsigned short* base, int slot, int lay) {
    return base + ((size_t)slot*3 + lay)*BH;
  };

  const unsigned short *A0h_,*A0l_,*A1h_,*A1l_,*A2h_,*A2l_,*W0_,*W1_,*W2_;
  int K1;
  if (l == 0) {
    A0h_ = xh + (size_t)t*BATCH*FEAT; A0l_ = xl + (size_t)t*BATCH*FEAT; K1 = FEAT;
    A1h_ = hp(hH,s1,0); A1l_ = hp(hL,s1,0);
    A2h_ = A1h_; A2l_ = A1l_;
    W0_ = Wih0p; W1_ = Whhp; W2_ = Whhp;
  } else if (l == 1) {
    A0h_ = hp(hH,s1,0); A0l_ = hp(hL,s1,0); K1 = HID;
    A1h_ = hp(hH,s1,1); A1l_ = hp(hL,s1,1);
    A2h_ = A1h_; A2l_ = A1l_;
    W0_ = Wf1p; W1_ = Whhp + (size_t)G4*HID; W2_ = W1_;
  } else if (l == 2) {
    A0h_ = hp(hH,s1,1); A0l_ = hp(hL,s1,1); K1 = HID;
    A1h_ = hp(hH,s2,0); A1l_ = hp(hL,s2,0);
    A2h_ = hp(hH,s1,2); A2l_ = hp(hL,s1,2);
    W0_ = Wf2p; W1_ = Wff2p; W2_ = Whhp + 2ull*G4*HID;
  } else {
    A0h_ = hp(hH,s1,2); A0l_ = hp(hL,s1,2); K1 = HID;
    A1h_ = hp(hH,s2,1); A1l_ = hp(hL,s2,1);
    A2h_ = hp(hH,s3,0); A2l_ = hp(hL,s3,0);
    W0_ = WoutC; W1_ = Wo2u; W2_ = Wo3u;
  }

  f32x4 z4 = {0.f,0.f,0.f,0.f};
  f32x4 acc[4][4];
  #pragma unroll
  for (int a = 0; a < 4; ++a) { acc[a][0]=z4; acc[a][1]=z4; acc[a][2]=z4; acc[a][3]=z4; }
  mm_core3<true>(smem, jt << 8, kz*512, 8, K1,
                 A0h_, A0l_, A1h_, A1l_, A2h_, A2l_, W0_, W1_, W2_, acc);

  // slab write (C/D layout: col=lane&15, row=(lane>>4)*4+r — m89/m91 verified)
  {
    const int lane = tid & 63, wave = tid >> 6;
    const int wr = wave >> 2, wc = wave & 3;
    const int rb = (lane >> 4) << 2, cbl = lane & 15;
    float* const slab = gpart + ((size_t)bid << 15);
    #pragma unroll
    for (int mi = 0; mi < 4; ++mi)
      #pragma unroll
      for (int ni = 0; ni < 4; ++ni)
        #pragma unroll
        for (int r = 0; r < 4; ++r) {
          const int row = (wr << 6) + (mi << 4) + rb + r;
          const int col = (wc << 6) + (ni << 4) + cbl;
          slab[(row << 8) + col] = acc[mi][ni][r];
        }
  }

  // ticket: last arrival of the KZ-group reduces + applies cell / writes out.
  asm volatile("s_waitcnt vmcnt(0)" ::: "memory");   // my slab stores complete to L2
  __syncthreads();
  if (tid == 0) {
    const unsigned old = __hip_atomic_fetch_add(&tk[gid*32], 1u,
                          __ATOMIC_ACQ_REL, __HIP_MEMORY_SCOPE_AGENT);
    lastf = (old == (unsigned)(KZ*(t+1) - 1));
  }
  __syncthreads();
  if (!lastf) return;

  const float* sb = gpart + ((size_t)(bid - kz) << 15);
  if (!isout) {
    // cell on 128 x 64 n-values (all 4 gates local)
    const float4* bp = (const float4*)(bperm + (l << 12) + (jt << 8));
    #pragma unroll
    for (int i = 0; i < 16; ++i) {
      const int e = i*512 + tid;          // 0..8191
      const int m = e >> 6, nl = e & 63;
      float4 g = bp[nl];
      for (int z = 0; z < KZ; ++z) {
        const float4 v = ((const float4*)(sb + ((size_t)z << 15) + (m << 8)))[nl];
        g.x += v.x; g.y += v.y; g.z += v.z; g.w += v.w;
      }
      const int n = (jt << 6) + nl;
      const size_t ci = (size_t)l*BH + (m << 10) + n;
      const float cn = sigf(g.y)*cst[ci] + sigf(g.x)*tanhf(g.z);
      cst[ci] = cn;
      const float h = sigf(g.w)*tanhf(cn);
      const size_t hi = ((size_t)(d & 3)*3 + l)*BH + (m << 10) + n;
      const unsigned short hh = f16_rne(h);
      hHw[hi] = hh; hLw[hi] = f16_rne(h - f16_tof(hh));
    }
  } else {
    // out(t) = sum of 6 slabs + bconst over 128 x 256 cols
    const float4* bc = (const float4*)(bconst + (jt << 8));
    float* const op = out + (size_t)t*BH;
    #pragma unroll
    for (int i = 0; i < 16; ++i) {
      const int e = i*512 + tid;          // 0..8191 float4s
      const int m = e >> 6, lc = e & 63;
      float4 v = bc[lc];
      for (int z = 0; z < 6; ++z) {
        const float4 w = ((const float4*)(sb + ((size_t)z << 15) + (m << 8)))[lc];
        v.x += w.x; v.y += w.y; v.z += w.z; v.w += w.w;
      }
      ((float4*)(op + (m << 10) + (jt << 8)))[lc] = v;
    }
  }
}

// ---------------- host ----------------

extern "C" void kernel_launch(void* const* d_in, const int* in_sizes, int n_in,
                              void* d_out, int out_size, void* d_ws, size_t ws_size,
                              hipStream_t stream) {
  const float* x    = (const float*)d_in[0];
  const float* Wih0 = (const float*)d_in[1];
  const float* Wihr = (const float*)d_in[2];
  const float* Whh  = (const float*)d_in[3];
  const float* bih  = (const float*)d_in[4];
  const float* bhh  = (const float*)d_in[5];
  const float* Wout = (const float*)d_in[6];
  const float* bout = (const float*)d_in[7];
  float* out = (float*)d_out;

  char* base = (char*)d_ws;
  size_t off = 0;
  auto alloc = [&](size_t bytes) -> char* {
    char* p = base + off;
    off = (off + bytes + 255) & ~(size_t)255;
    return p;
  };
  float* gpart = (float*)alloc(232ull*32768*4);                 // 30.4 MB
  float* cst   = (float*)alloc(3ull*BH*4);
  float* bperm = (float*)alloc(3ull*G4*4);
  float* bconst= (float*)alloc((size_t)HID*4);
  unsigned short* hH = (unsigned short*)alloc(4ull*3*BH*2);     // ring [4][3][BH]
  unsigned short* hL = (unsigned short*)alloc(4ull*3*BH*2);
  unsigned short* x_h = (unsigned short*)alloc((size_t)SEQ*BATCH*FEAT*2);
  unsigned short* x_l = (unsigned short*)alloc((size_t)SEQ*BATCH*FEAT*2);
  unsigned short* Wih0p = (unsigned short*)alloc((size_t)G4*FEAT*2);
  unsigned short* Whhp  = (unsigned short*)alloc(3ull*G4*HID*2);
  unsigned short* Wf1p  = (unsigned short*)alloc((size_t)G4*HID*2);
  unsigned short* Wf2p  = (unsigned short*)alloc((size_t)G4*HID*2);
  unsigned short* Wf2u  = (unsigned short*)alloc((size_t)G4*HID*2);
  unsigned short* Wff2p = (unsigned short*)alloc((size_t)G4*HID*2);
  unsigned short* WoutC = (unsigned short*)alloc((size_t)HID*HID*2);
  unsigned short* WoutT = (unsigned short*)alloc((size_t)HID*HID*2);
  unsigned short* Wo2u  = (unsigned short*)alloc((size_t)HID*HID*2);
  unsigned short* Wo3u  = (unsigned short*)alloc((size_t)HID*HID*2);
  unsigned* tk = (unsigned*)alloc(52ull*32*4);
  // f16 staging of Wihr aliases gpart (dead before first diag launch)
  unsigned short* Wtmp = (unsigned short*)gpart;                // 16.8 MB <= 30.4

  // --- one-time conversions & folds ---
  conv16<<<2048, 256, 0, stream>>>(Wihr, Wtmp, 2*G4*HID/4);
  conv16<<<1024, 256, 0, stream>>>(Wout, WoutC, HID*HID/4);
  transp16<<<4096, 256, 0, stream>>>(Wout, WoutT);
  conv_perm16<<<2048, 256, 0, stream>>>(Wih0, Wih0p, G4*FEAT/4, 7);
  for (int l = 0; l < 3; ++l)
    conv_perm16<<<2048, 256, 0, stream>>>(Whh + (size_t)l*G4*HID,
        Whhp + (size_t)l*G4*HID, G4*HID/4, 8);
  conv16_hilo<<<2048, 256, 0, stream>>>(x, x_h, x_l, SEQ*BATCH*FEAT/4);

  wfuse_kernel<<<dim3(32,4), 512, 0, stream>>>(Wtmp, WoutT, nullptr, Wf1p);
  wfuse_kernel<<<dim3(32,4), 512, 0, stream>>>(Wtmp + (size_t)G4*HID, WoutT, Wf2u, Wf2p);
  wfuse_kernel<<<dim3(32,4), 512, 0, stream>>>(Wf2u, WoutT, nullptr, Wff2p);
  wfuse_kernel<<<dim3(8,4),  512, 0, stream>>>(WoutC, WoutT, Wo2u, nullptr);
  wfuse_kernel<<<dim3(8,4),  512, 0, stream>>>(Wo2u, WoutT, Wo3u, nullptr);

  bias_perm<<<48, 256, 0, stream>>>(bih, bhh, bperm);
  gemvf<<<16, 256, 0, stream>>>(Wihr,                     bout, bperm + G4,   G4, 1);
  gemvf<<<16, 256, 0, stream>>>(Wihr + (size_t)G4*HID,    bout, bperm + 2*G4, G4, 1);
  gemvh<<<16, 256, 0, stream>>>(Wf2u,                     bout, bperm + 2*G4, G4, 1);
  bcopy<<<4, 256, 0, stream>>>(bout, bconst);
  gemvf<<<4, 256, 0, stream>>>(Wout, bout, bconst, HID, 0);
  gemvh<<<4, 256, 0, stream>>>(Wo2u, bout, bconst, HID, 0);

  // zero recurrent state + tickets each call (inside graph)
  hipMemsetAsync(cst, 0, 3ull*BH*4, stream);
  hipMemsetAsync(hH, 0, 4ull*3*BH*2, stream);
  hipMemsetAsync(hL, 0, 4ull*3*BH*2, stream);
  hipMemsetAsync(tk, 0, 52ull*32*4, stream);

  for (int d = 0; d < SEQ + 3; ++d) {
    diag_kernel<<<232, 512, 0, stream>>>(d, x_h, x_l, hH, hL, hH, hL,
        Wih0p, Whhp, Wf1p, Wf2p, Wff2p, WoutC, Wo2u, Wo3u,
        bperm, bconst, cst, gpart, tk, out);
  }
}

// Round 10
// 6895.359 us; speedup vs baseline: 2.3642x; 2.3642x over previous
//
#include <hip/hip_runtime.h>
#include <cmath>

#define SEQ  256
#define BATCH 128
#define FEAT 512
#define HID  1024
#define G4   4096
#define BH (BATCH*HID)

typedef __attribute__((ext_vector_type(8))) _Float16 f16x8;
typedef __attribute__((ext_vector_type(4))) float f32x4;

__device__ __forceinline__ unsigned short f16_rne(float f) {
  _Float16 h = (_Float16)f;
  return __builtin_bit_cast(unsigned short, h);
}
__device__ __forceinline__ float f16_tof(unsigned short s) {
  return (float)__builtin_bit_cast(_Float16, s);
}
__device__ __forceinline__ void gload16(const unsigned short* g, unsigned short* l) {
  __builtin_amdgcn_global_load_lds(
      (const __attribute__((address_space(1))) unsigned int*)g,
      (__attribute__((address_space(3))) unsigned int*)l, 16, 0, 0);
}
__device__ __forceinline__ float sigf(float x) { return 1.f/(1.f+expf(-x)); }

// ---- sc0/sc1 (system-coherent, L3-direct) access helpers: no cached copies
// of slab data ever exist in L1/L2, so relaxed atomics suffice for sync. ----
__device__ __forceinline__ void st1sc(float* p, float v) {
  asm volatile("global_store_dword %0, %1, off sc0 sc1" :: "v"(p), "v"(v) : "memory");
}
__device__ __forceinline__ f32x4 ld4sc(const float* p) {
  f32x4 r;
  asm volatile("global_load_dwordx4 %0, %1, off sc0 sc1" : "=v"(r) : "v"(p) : "memory");
  return r;
}
__device__ __forceinline__ float ld1sc(const float* p) {
  float r;
  asm volatile("global_load_dword %0, %1, off sc0 sc1" : "=v"(r) : "v"(p) : "memory");
  return r;
}
__device__ __forceinline__ void wait0() {
  asm volatile("s_waitcnt vmcnt(0)" ::: "memory");
  __builtin_amdgcn_sched_barrier(0);      // rule #18: fence dependent reg uses
}

// ---------------- setup kernels (once per call) ----------------

__global__ __launch_bounds__(256)
void conv16(const float* __restrict__ src, unsigned short* __restrict__ dst, int n4) {
  for (int i = blockIdx.x*256 + threadIdx.x; i < n4; i += gridDim.x*256) {
    const float4 v = ((const float4*)src)[i];
    ushort4 h;
    h.x = f16_rne(v.x); h.y = f16_rne(v.y); h.z = f16_rne(v.z); h.w = f16_rne(v.w);
    ((ushort4*)dst)[i] = h;
  }
}

__global__ __launch_bounds__(256)
void conv16_hilo(const float* __restrict__ src, unsigned short* __restrict__ hi,
                 unsigned short* __restrict__ lo, int n4) {
  for (int i = blockIdx.x*256 + threadIdx.x; i < n4; i += gridDim.x*256) {
    const float4 v = ((const float4*)src)[i];
    ushort4 h, l;
    h.x = f16_rne(v.x); l.x = f16_rne(v.x - f16_tof(h.x));
    h.y = f16_rne(v.y); l.y = f16_rne(v.y - f16_tof(h.y));
    h.z = f16_rne(v.z); l.z = f16_rne(v.z - f16_tof(h.z));
    h.w = f16_rne(v.w); l.w = f16_rne(v.w - f16_tof(h.w));
    ((ushort4*)hi)[i] = h; ((ushort4*)lo)[i] = l;
  }
}

// WoutT[c][k] = f16(Wout[k][c])
__global__ __launch_bounds__(256)
void transp16(const float* __restrict__ src, unsigned short* __restrict__ dst) {
  const int i = blockIdx.x*256 + threadIdx.x;   // 1M
  const int k = i >> 10, c = i & 1023;
  dst[(c << 10) + k] = f16_rne(src[i]);
}

// f32 -> f16 with gate-row permutation: r = g*1024+n -> prow = n*4+g
__global__ __launch_bounds__(256)
void conv_perm16(const float* __restrict__ src, unsigned short* __restrict__ dst,
                 int n4, int ksh) {
  for (int i = blockIdx.x*256 + threadIdx.x; i < n4; i += gridDim.x*256) {
    const float4 v = ((const float4*)src)[i];
    const int row = i >> ksh, cq = i & ((1 << ksh) - 1);
    const int prow = ((row & 1023) << 2) | (row >> 10);
    ushort4 h;
    h.x = f16_rne(v.x); h.y = f16_rne(v.y); h.z = f16_rne(v.z); h.w = f16_rne(v.w);
    ((ushort4*)dst)[(prow << ksh) + cq] = h;
  }
}

// bperm[l][prow] = bih + bhh (gate-permuted, f32)
__global__ __launch_bounds__(256)
void bias_perm(const float* __restrict__ bih, const float* __restrict__ bhh,
               float* __restrict__ bperm) {
  const int i = blockIdx.x*256 + threadIdx.x;
  if (i >= 3*G4) return;
  const int l = i >> 12, r = i & 4095;
  const int prow = ((r & 1023) << 2) | (r >> 10);
  bperm[(l << 12) + prow] = bih[i] + bhh[i];
}

// dst[prow(r)] += W[r,:] . b   (f32 weights, gate-permuted dest)
__global__ __launch_bounds__(256)
void gemvf(const float* __restrict__ W, const float* __restrict__ b,
           float* __restrict__ dst, int nrows) {
  const int r = blockIdx.x*256 + threadIdx.x;
  if (r >= nrows) return;
  const float4* wr = (const float4*)(W + (size_t)r*HID);
  float acc = 0.f;
  for (int k = 0; k < 256; ++k) {
    const float4 w = wr[k]; const float4 bb = ((const float4*)b)[k];
    acc += w.x*bb.x + w.y*bb.y + w.z*bb.z + w.w*bb.w;
  }
  dst[((r & 1023) << 2) | (r >> 10)] += acc;
}

// ---------------- split-precision f16 MFMA GEMM core (R7/R8-verified) ----
// P2: Ah*W + Al*W (A fp16 hi/lo); !P2: Ah*W only. BM=128, BN=256, BK=64;
// 8 waves (2x4), wave tile 64x64. Double-buffered LDS (128 KB) +
// global_load_lds(16B) + XOR-(row&7) swizzle. A/W seg1 stride K1, seg2 1024.
template<int MI, int NI, int WRN, int WCN, bool P2>
__device__ __forceinline__ void mm_core(
    unsigned short* lds, int n0, int kstart, int nch,
    const unsigned short* A1h, const unsigned short* A1l, int K1,
    const unsigned short* A2h, const unsigned short* A2l,
    const unsigned short* W1, const unsigned short* W2,
    f32x4 acc[MI][NI])
{
  constexpr int AROWS = WRN*MI*16;          // 128
  constexpr int WROWS = WCN*NI*16;          // 256
  constexpr int OAl = AROWS*64;
  constexpr int OW  = 2*AROWS*64;
  constexpr int STRIDE = (2*AROWS + WROWS)*64;
  constexpr int NLD = (2*AROWS + WROWS)/64; // 8
  const int tid = threadIdx.x;
  const int lane = tid & 63, wave = tid >> 6;
  const int wr = wave / WCN, wc = wave % WCN;
  const int rl = lane >> 3, cc = lane & 7;
  const int gcol = (cc ^ rl) << 3;

  auto stage = [&](int ch) {
    const int kg = kstart + (ch << 6);
    const unsigned short *pAh, *pAl, *pW; int sA;
    if (kg < K1) { pAh=A1h+kg; pAl=A1l+kg; pW=W1+kg; sA=K1; }
    else { const int k2 = kg - K1; pAh=A2h+k2; pAl=A2l+k2; pW=W2+k2; sA=1024; }
    unsigned short* const db = lds + (ch & 1)*STRIDE;
    #pragma unroll
    for (int q = 0; q < NLD; ++q) {
      const int g = wave*NLD + q;
      if (g < AROWS/8)      gload16(pAh + (size_t)(g*8 + rl)*sA + gcol,            db + g*512);
      else if (g < AROWS/4) gload16(pAl + (size_t)((g-AROWS/8)*8 + rl)*sA + gcol,  db + g*512);
      else                  gload16(pW  + (size_t)(n0 + (g-AROWS/4)*8 + rl)*( (kstart+(ch<<6))<K1 ? sA : 1024 ) + gcol, db + g*512);
    }
  };

  stage(0);
  for (int ch = 0; ch < nch; ++ch) {
    if (ch + 1 < nch) {
      stage(ch + 1);
      asm volatile("s_waitcnt vmcnt(8)" ::: "memory");
    } else {
      asm volatile("s_waitcnt vmcnt(0)" ::: "memory");
    }
    __builtin_amdgcn_sched_barrier(0);
    __builtin_amdgcn_s_barrier();
    const unsigned short* const cb = lds + (ch & 1)*STRIDE;
    #pragma unroll
    for (int kh = 0; kh < 2; ++kh) {
      const int j0 = (kh << 2) + (lane >> 4);
      f16x8 ah[MI], al[MI], bh[NI];
      #pragma unroll
      for (int mi = 0; mi < MI; ++mi) {
        const int row = wr*(MI*16) + (mi << 4) + (lane & 15);
        const int off = row*64 + ((j0 ^ (row & 7)) << 3);
        ah[mi] = *(const f16x8*)(cb + off);
        if constexpr (P2) al[mi] = *(const f16x8*)(cb + OAl + off);
      }
      #pragma unroll
      for (int ni = 0; ni < NI; ++ni) {
        const int wrow = wc*(NI*16) + (ni << 4) + (lane & 15);
        const int off = wrow*64 + ((j0 ^ (wrow & 7)) << 3);
        bh[ni] = *(const f16x8*)(cb + OW + off);
      }
      #pragma unroll
      for (int mi = 0; mi < MI; ++mi)
        #pragma unroll
        for (int ni = 0; ni < NI; ++ni) {
          acc[mi][ni] = __builtin_amdgcn_mfma_f32_16x16x32_f16(ah[mi], bh[ni], acc[mi][ni], 0,0,0);
          if constexpr (P2)
            acc[mi][ni] = __builtin_amdgcn_mfma_f32_16x16x32_f16(al[mi], bh[ni], acc[mi][ni], 0,0,0);
        }
    }
    __builtin_amdgcn_s_barrier();
  }
}

// ---------------- Wfused = Wihr(f16) @ WoutT -> gate-permuted f16 ----------------
__global__ __launch_bounds__(512, 2)
void wfuse_kernel(const unsigned short* __restrict__ A,
                  const unsigned short* __restrict__ WT,
                  unsigned short* __restrict__ dstP)
{
  __shared__ unsigned short smem[2*32768];
  const int mb = blockIdx.x, jy = blockIdx.y;
  const unsigned short* Ar = A + (size_t)(mb*128)*HID;
  f32x4 z4 = {0.f,0.f,0.f,0.f};
  f32x4 acc[4][4];
  #pragma unroll
  for (int a = 0; a < 4; ++a) { acc[a][0]=z4; acc[a][1]=z4; acc[a][2]=z4; acc[a][3]=z4; }
  mm_core<4,4,2,4,false>(smem, jy << 8, 0, 16, Ar, Ar, 1024, Ar, Ar, WT, WT, acc);

  const int lane = threadIdx.x & 63, wave = threadIdx.x >> 6;
  const int wr = wave >> 2, wc = wave & 3;
  const int rb = (lane >> 4) << 2, cbl = lane & 15;
  #pragma unroll
  for (int mi = 0; mi < 4; ++mi)
    #pragma unroll
    for (int ni = 0; ni < 4; ++ni)
      #pragma unroll
      for (int r = 0; r < 4; ++r) {
        const int row = mb*128 + (wr << 6) + (mi << 4) + rb + r;
        const int col = (jy << 8) + (wc << 6) + (ni << 4) + cbl;
        dstP[((size_t)(((row & 1023) << 2) | (row >> 10)) << 10) + col] = f16_rne(acc[mi][ni][r]);
      }
}

// ---------------- fused per-diagonal kernel (ONE launch per diag) ----------------
// 224 blocks, all co-resident (128 KB LDS -> 1 block/CU):
//   [0,64)    l0 gates  jt=bid>>2, kz=bid&3 (KZ=4), K=1536 = x|h0
//   [64,128)  l1 gates  (KZ=4), K=2048 = s0|h1   (W = Wfused1 perm | Whh1 perm)
//   [128,136) l1 ext    jtf=w>>1, kz=w&1 (KZ=2): s0 @ Wout rows jtf*256
//   [136,200) l2 gates  (KZ=4), K=2048 = s1|h2
//   [200,208) l2 ext    (KZ=2): s1 @ Wout
//   [208,224) out       jt=u>>2, kz=u&3 (KZ=4): s2 @ Wout, K=1024
// Slabs via sc0/sc1 (L3-direct); relaxed system tickets; every group member
// spins then reduces its 1/KZ m-shard and applies cell / writes out.
__global__ __launch_bounds__(512, 2)
void diag_fused(int d,
    const unsigned short* __restrict__ x_h, const unsigned short* __restrict__ x_l,
    unsigned short* __restrict__ hH, unsigned short* __restrict__ hL,   // [2][3][BH]
    unsigned short* __restrict__ sH, unsigned short* __restrict__ sL,   // [2][3][BH]
    const unsigned short* __restrict__ Wih0p, const unsigned short* __restrict__ Whhp,
    const unsigned short* __restrict__ Wf1p,  const unsigned short* __restrict__ Wf2p,
    const unsigned short* __restrict__ WoutC,
    const float* __restrict__ bperm, const float* __restrict__ bout,
    float* __restrict__ cst, float* __restrict__ gpart,
    unsigned* __restrict__ tk, float* __restrict__ out)
{
  __shared__ unsigned short smem[2*32768];   // 128 KB
  const int bid = blockIdx.x, tid = threadIdx.x;
  const int p = d & 1, rp = 1 - p;           // write slot p, read slot rp

  int l, jt, kz, KZ, gid, role;              // role 0=gates 1=ext 2=out
  if (bid < 64)       { l=0; jt=bid>>2;            kz=bid&3; KZ=4; gid=jt;    role=0; }
  else if (bid < 128) { l=1; int u=bid-64;  jt=u>>2; kz=u&3; KZ=4; gid=16+jt; role=0; }
  else if (bid < 136) { l=1; int w=bid-128; jt=w>>1; kz=w&1; KZ=2; gid=48+jt; role=1; }
  else if (bid < 200) { l=2; int u=bid-136; jt=u>>2; kz=u&3; KZ=4; gid=32+jt; role=0; }
  else if (bid < 208) { l=2; int w=bid-200; jt=w>>1; kz=w&1; KZ=2; gid=52+jt; role=1; }
  else                { l=3; int u=bid-208; jt=u>>2; kz=u&3; KZ=4; gid=56+jt; role=2; }
  const int t = d - ((role==2) ? 3 : l);
  if (t < 0 || t >= SEQ) return;

  // ---- GEMM operand selection ----
  const unsigned short *A1h_, *A1l_, *A2h_, *A2l_, *W1_, *W2_;
  int K1, kstart, nch;
  if (role == 0) {
    if (l == 0) {
      A1h_ = x_h + (size_t)t*BATCH*FEAT; A1l_ = x_l + (size_t)t*BATCH*FEAT;
      K1 = FEAT; W1_ = Wih0p; kstart = kz*384; nch = 6;
    } else {
      A1h_ = sH + ((size_t)rp*3 + (l-1))*BH; A1l_ = sL + ((size_t)rp*3 + (l-1))*BH;
      K1 = HID; W1_ = (l==1) ? Wf1p : Wf2p; kstart = kz*512; nch = 8;
    }
    A2h_ = hH + ((size_t)rp*3 + l)*BH; A2l_ = hL + ((size_t)rp*3 + l)*BH;
    W2_  = Whhp + (size_t)l*G4*HID;
  } else if (role == 1) {
    A1h_ = sH + ((size_t)rp*3 + (l-1))*BH; A1l_ = sL + ((size_t)rp*3 + (l-1))*BH;
    K1 = HID; W1_ = WoutC; W2_ = WoutC; A2h_ = A1h_; A2l_ = A1l_;
    kstart = kz*512; nch = 8;
  } else {
    A1h_ = sH + ((size_t)rp*3 + 2)*BH; A1l_ = sL + ((size_t)rp*3 + 2)*BH;
    K1 = HID; W1_ = WoutC; W2_ = WoutC; A2h_ = A1h_; A2l_ = A1l_;
    kstart = kz*256; nch = 4;
  }

  f32x4 z4 = {0.f,0.f,0.f,0.f};
  f32x4 acc[4][4];
  #pragma unroll
  for (int a = 0; a < 4; ++a) { acc[a][0]=z4; acc[a][1]=z4; acc[a][2]=z4; acc[a][3]=z4; }
  mm_core<4,4,2,4,true>(smem, jt << 8, kstart, nch, A1h_, A1l_, K1,
                        A2h_, A2l_, W1_, W2_, acc);

  // ---- slab write via sc0/sc1 (L3-direct; C/D layout m89/m91) ----
  {
    const int lane = tid & 63, wave = tid >> 6;
    const int wr = wave >> 2, wc = wave & 3;
    const int rb = (lane >> 4) << 2, cbl = lane & 15;
    float* const slab = gpart + ((size_t)bid << 15);
    #pragma unroll
    for (int mi = 0; mi < 4; ++mi)
      #pragma unroll
      for (int ni = 0; ni < 4; ++ni)
        #pragma unroll
        for (int r = 0; r < 4; ++r) {
          const int row = (wr << 6) + (mi << 4) + rb + r;
          const int col = (wc << 6) + (ni << 4) + cbl;
          st1sc(slab + (row << 8) + col, acc[mi][ni][r]);
        }
  }

  // ---- arrive (relaxed system ticket; stores drained first) ----
  asm volatile("s_waitcnt vmcnt(0)" ::: "memory");
  __syncthreads();
  if (tid == 0)
    __hip_atomic_fetch_add(&tk[gid*32], 1u, __ATOMIC_RELAXED, __HIP_MEMORY_SCOPE_SYSTEM);
  if (role == 1) return;   // ext blocks: produce only

  // ---- spin: own group, plus ext group for gates l>=1 ----
  {
    unsigned* a = &tk[gid*32];
    const unsigned ta = (unsigned)(KZ*(t+1));
    unsigned* b = nullptr; unsigned tb = 0;
    if (role == 0 && l) {
      b = &tk[(48 + (l-1)*4 + (jt >> 2))*32];
      tb = (unsigned)(2*(t+1));
    }
    if (tid == 0) {
      while ((int)(__hip_atomic_load(a, __ATOMIC_RELAXED, __HIP_MEMORY_SCOPE_SYSTEM) - ta) < 0)
        __builtin_amdgcn_s_sleep(4);
      if (b)
        while ((int)(__hip_atomic_load(b, __ATOMIC_RELAXED, __HIP_MEMORY_SCOPE_SYSTEM) - tb) < 0)
          __builtin_amdgcn_s_sleep(4);
    }
    __syncthreads();
  }

  // ---- reduce my 1/KZ m-shard + cell / out ----
  const float* gb = gpart + ((size_t)(bid - kz) << 15);
  const int m0 = kz << 5;    // 32 m-rows per shard
  if (role == 0) {
    const float* eb = l ? gpart + ((size_t)((l==1 ? 128 : 200) + ((jt >> 2) << 1)) << 15)
                        : nullptr;
    const int lcb = (jt & 3) << 6;
    #pragma unroll
    for (int it = 0; it < 4; ++it) {
      const int e = it*512 + tid;          // 0..2047
      const int m = m0 + (e >> 6), nl = e & 63;
      const int o = (m << 8) + (nl << 2);
      const f32x4 a0 = ld4sc(gb + o);
      const f32x4 a1 = ld4sc(gb + (1u << 15) + o);
      const f32x4 a2 = ld4sc(gb + (2u << 15) + o);
      const f32x4 a3 = ld4sc(gb + (3u << 15) + o);
      float e0 = 0.f, e1 = 0.f;
      if (l) {
        e0 = ld1sc(eb + (m << 8) + lcb + nl);
        e1 = ld1sc(eb + (1u << 15) + (m << 8) + lcb + nl);
      }
      wait0();
      const int n = (jt << 6) + nl;
      const float4 bp = ((const float4*)(bperm + (l << 12)))[n];
      const float gi = a0.x + a1.x + a2.x + a3.x + bp.x;
      const float gf = a0.y + a1.y + a2.y + a3.y + bp.y;
      const float gg = a0.z + a1.z + a2.z + a3.z + bp.z;
      const float go = a0.w + a1.w + a2.w + a3.w + bp.w;
      const size_t ci = (size_t)l*BH + (m << 10) + n;
      const float cn = sigf(gf)*cst[ci] + sigf(gi)*tanhf(gg);
      cst[ci] = cn;
      const float h = sigf(go)*tanhf(cn);
      const size_t wi = ((size_t)p*3 + l)*BH + (m << 10) + n;
      const unsigned short hh = f16_rne(h);
      hH[wi] = hh; hL[wi] = f16_rne(h - f16_tof(hh));
      float s = h;
      if (l) s += bout[n] + e0 + e1;
      const unsigned short ss = f16_rne(s);
      sH[wi] = ss; sL[wi] = f16_rne(s - f16_tof(ss));
    }
  } else {
    float* const op = out + (size_t)t*BH;
    #pragma unroll
    for (int it = 0; it < 4; ++it) {
      const int e = it*512 + tid;          // 0..2047
      const int m = m0 + (e >> 6), q = e & 63;
      const int o = (m << 8) + (q << 2);
      const f32x4 a0 = ld4sc(gb + o);
      const f32x4 a1 = ld4sc(gb + (1u << 15) + o);
      const f32x4 a2 = ld4sc(gb + (2u << 15) + o);
      const f32x4 a3 = ld4sc(gb + (3u << 15) + o);
      wait0();
      const float4 bc = ((const float4*)bout)[(jt << 6) + q];
      float4 v;
      v.x = a0.x + a1.x + a2.x + a3.x + bc.x;
      v.y = a0.y + a1.y + a2.y + a3.y + bc.y;
      v.z = a0.z + a1.z + a2.z + a3.z + bc.z;
      v.w = a0.w + a1.w + a2.w + a3.w + bc.w;
      *(float4*)(op + (m << 10) + (jt << 8) + (q << 2)) = v;
    }
  }
}

// ---------------- host ----------------

extern "C" void kernel_launch(void* const* d_in, const int* in_sizes, int n_in,
                              void* d_out, int out_size, void* d_ws, size_t ws_size,
                              hipStream_t stream) {
  const float* x    = (const float*)d_in[0];
  const float* Wih0 = (const float*)d_in[1];
  const float* Wihr = (const float*)d_in[2];
  const float* Whh  = (const float*)d_in[3];
  const float* bih  = (const float*)d_in[4];
  const float* bhh  = (const float*)d_in[5];
  const float* Wout = (const float*)d_in[6];
  const float* bout = (const float*)d_in[7];
  float* out = (float*)d_out;

  char* base = (char*)d_ws;
  size_t off = 0;
  auto alloc = [&](size_t bytes) -> char* {
    char* p = base + off;
    off = (off + bytes + 255) & ~(size_t)255;
    return p;
  };
  float* gpart = (float*)alloc(224ull*32768*4);               // 29.4 MB
  float* cst   = (float*)alloc(3ull*BH*4);
  float* bperm = (float*)alloc(3ull*G4*4);
  unsigned short* hH = (unsigned short*)alloc(2ull*3*BH*2);
  unsigned short* hL = (unsigned short*)alloc(2ull*3*BH*2);
  unsigned short* sH = (unsigned short*)alloc(2ull*3*BH*2);
  unsigned short* sL = (unsigned short*)alloc(2ull*3*BH*2);
  unsigned short* x_h = (unsigned short*)alloc((size_t)SEQ*BATCH*FEAT*2);
  unsigned short* x_l = (unsigned short*)alloc((size_t)SEQ*BATCH*FEAT*2);
  unsigned short* Wih0p = (unsigned short*)alloc((size_t)G4*FEAT*2);
  unsigned short* Whhp  = (unsigned short*)alloc(3ull*G4*HID*2);
  unsigned short* Wf1p  = (unsigned short*)alloc((size_t)G4*HID*2);
  unsigned short* Wf2p  = (unsigned short*)alloc((size_t)G4*HID*2);
  unsigned short* WoutC = (unsigned short*)alloc((size_t)HID*HID*2);
  unsigned short* WoutT = (unsigned short*)alloc((size_t)HID*HID*2);
  unsigned* tk = (unsigned*)alloc(60ull*32*4);
  // f16 staging of Wihr aliases gpart (dead before first diag launch)
  unsigned short* Wtmp = (unsigned short*)gpart;              // 16.8 MB <= 29.4

  // one-time conversions & folds
  conv16<<<2048, 256, 0, stream>>>(Wihr, Wtmp, 2*G4*HID/4);
  conv16<<<1024, 256, 0, stream>>>(Wout, WoutC, HID*HID/4);
  transp16<<<4096, 256, 0, stream>>>(Wout, WoutT);
  conv_perm16<<<2048, 256, 0, stream>>>(Wih0, Wih0p, G4*FEAT/4, 7);
  for (int l = 0; l < 3; ++l)
    conv_perm16<<<2048, 256, 0, stream>>>(Whh + (size_t)l*G4*HID,
        Whhp + (size_t)l*G4*HID, G4*HID/4, 8);
  conv16_hilo<<<2048, 256, 0, stream>>>(x, x_h, x_l, SEQ*BATCH*FEAT/4);
  wfuse_kernel<<<dim3(32,4), 512, 0, stream>>>(Wtmp,                    WoutT, Wf1p);
  wfuse_kernel<<<dim3(32,4), 512, 0, stream>>>(Wtmp + (size_t)G4*HID,   WoutT, Wf2p);
  bias_perm<<<48, 256, 0, stream>>>(bih, bhh, bperm);
  gemvf<<<16, 256, 0, stream>>>(Wihr,                  bout, bperm + G4,   G4);
  gemvf<<<16, 256, 0, stream>>>(Wihr + (size_t)G4*HID, bout, bperm + 2*G4, G4);

  // zero recurrent state + tickets each call (inside graph)
  hipMemsetAsync(cst, 0, 3ull*BH*4, stream);
  hipMemsetAsync(hH, 0, 2ull*3*BH*2, stream);
  hipMemsetAsync(hL, 0, 2ull*3*BH*2, stream);
  hipMemsetAsync(tk, 0, 60ull*32*4, stream);

  for (int d = 0; d < SEQ + 3; ++d) {
    diag_fused<<<224, 512, 0, stream>>>(d, x_h, x_l, hH, hL, sH, sL,
        Wih0p, Whhp, Wf1p, Wf2p, WoutC, bperm, bout, cst, gpart, tk, out);
  }
}